// Round 14
// baseline (1097.053 us; speedup 1.0000x reference)
//
#include <hip/hip_runtime.h>
#include <hip/hip_fp16.h>
#include <cstddef>

#define BB    4
#define NN    10000
#define EE    160000
#define BN    40000      // BB*NN
#define HISTC 8
#define PREDC 12
#define TSTEP 20         // HIST+PRED
#define FEX   8
#define HIDC  64
#define EHID  32
#define EOUTC 30
#define GOUTC 13
#define GINC  22         // GOUTC + 9

typedef float v2f __attribute__((ext_vector_type(2)));
typedef _Float16 v2h __attribute__((ext_vector_type(2)));

struct alignas(16) WPack {      // 128 B: one layer-2 output channel
    __half2 w[16];   // w2 row (32 halves)
    float   nw[14];  // folded n_w row (13 + pad)
    float   b2;
    float   pad;
};

__device__ __forceinline__ float fast_rcp(float x) { return __builtin_amdgcn_rcpf(x); }
__device__ __forceinline__ float sigm(float x) {
    return fast_rcp(1.0f + __expf(-x));
}
__device__ __forceinline__ v2f sigm2(v2f x) {
    v2f r; r.x = sigm(x.x); r.y = sigm(x.y); return r;
}
__device__ __forceinline__ float tanh_fast(float x) {
    x = fminf(fmaxf(x, -15.0f), 15.0f);
    float e = __expf(2.0f * x);
    return (e - 1.0f) * fast_rcp(e + 1.0f);
}

__device__ __forceinline__ float dot2(__half2 a, __half2 b, float c) {
#if __has_builtin(__builtin_amdgcn_fdot2)
    union { __half2 h; v2h v; } ua, ub;
    ua.h = a; ub.h = b;
    return __builtin_amdgcn_fdot2(ua.v, ub.v, c, false);
#else
    float2 fa = __half22float2(a), fb = __half22float2(b);
    return c + fa.x * fb.x + fa.y * fb.y;
#endif
}

// ---------------- edge_attr stats ---------------------------------------------
__global__ __launch_bounds__(256) void stats1_kernel(const float* __restrict__ ea,
                                                     double* __restrict__ part) {
    __shared__ double sm[256][4];
    int tid = threadIdx.x;
    double s0 = 0, s1 = 0, q0 = 0, q1 = 0;
    for (int e = blockIdx.x * 256 + tid; e < EE; e += 256 * 256) {
        float2 v = reinterpret_cast<const float2*>(ea)[e];
        double v0 = (double)v.x, v1 = (double)v.y;
        s0 += v0; q0 += v0 * v0;
        s1 += v1; q1 += v1 * v1;
    }
    sm[tid][0] = s0; sm[tid][1] = s1; sm[tid][2] = q0; sm[tid][3] = q1;
    __syncthreads();
    for (int off = 128; off > 0; off >>= 1) {
        if (tid < off)
            for (int k = 0; k < 4; k++) sm[tid][k] += sm[tid + off][k];
        __syncthreads();
    }
    if (tid == 0) {
        part[blockIdx.x * 4 + 0] = sm[0][0];
        part[blockIdx.x * 4 + 1] = sm[0][1];
        part[blockIdx.x * 4 + 2] = sm[0][2];
        part[blockIdx.x * 4 + 3] = sm[0][3];
    }
}

__global__ __launch_bounds__(256) void stats2_kernel(const double* __restrict__ part,
                                                     float* __restrict__ stats) {
    __shared__ double sm[256][4];
    int tid = threadIdx.x;
    sm[tid][0] = part[tid * 4 + 0];
    sm[tid][1] = part[tid * 4 + 1];
    sm[tid][2] = part[tid * 4 + 2];
    sm[tid][3] = part[tid * 4 + 3];
    __syncthreads();
    for (int off = 128; off > 0; off >>= 1) {
        if (tid < off)
            for (int k = 0; k < 4; k++) sm[tid][k] += sm[tid + off][k];
        __syncthreads();
    }
    if (tid == 0) {
        double m0 = sm[0][0] / EE, m1 = sm[0][1] / EE;
        double v0 = (sm[0][2] - sm[0][0] * sm[0][0] / EE) / (double)(EE - 1);
        double v1 = (sm[0][3] - sm[0][1] * sm[0][1] / EE) / (double)(EE - 1);
        float sd0 = fmaxf((float)sqrt(v0 > 0 ? v0 : 0.0), 1e-6f);
        float sd1 = fmaxf((float)sqrt(v1 > 0 ? v1 : 0.0), 1e-6f);
        stats[0] = (float)m0; stats[1] = (float)m1;
        stats[2] = 1.0f / sd0; stats[3] = 1.0f / sd1;
    }
}

// ---------------- per-edge precompute -----------------------------------------
__global__ __launch_bounds__(256) void edgepre_kernel(
    const float* __restrict__ ea, const float* __restrict__ stats,
    float4* __restrict__ epre4)
{
    int e = blockIdx.x * 256 + threadIdx.x;
    if (e >= EE) return;
    float2 v = reinterpret_cast<const float2*>(ea)[e];
    float4 r;
    r.x = (v.x - stats[0]) * stats[2];
    r.y = (v.y - stats[1]) * stats[3];
    r.z = 1.0f / fmaxf(v.x, 1e-3f);
    r.w = v.y;
    epre4[e] = r;
}

// ---------------- weight conversion + WPack build (once per call) -------------
__global__ __launch_bounds__(256) void cvtw_kernel(
    const float* __restrict__ wi, const float* __restrict__ wh,
    const float* __restrict__ ew2, const float* __restrict__ eb2,
    const float* __restrict__ nw,
    __half* __restrict__ wi_h, __half* __restrict__ wh_h,
    WPack* __restrict__ wpack)
{
    int i = blockIdx.x * 256 + threadIdx.x;
    if (i < 192 * GINC) wi_h[i] = __float2half(wi[i]);
    if (i < 192 * HIDC) wh_h[i] = __float2half(wh[i]);
    if (i < EOUTC) {
        WPack wp;
        #pragma unroll
        for (int q = 0; q < 16; q++)
            wp.w[q] = __floats2half2_rn(ew2[(2 * q) * EOUTC + i],
                                        ew2[(2 * q + 1) * EOUTC + i]);
        #pragma unroll
        for (int j = 0; j < GOUTC; j++) wp.nw[j] = nw[i * GOUTC + j];
        wp.nw[13] = 0.f;
        wp.b2 = eb2[i];
        wp.pad = 0.f;
        wpack[i] = wp;
    }
}

// ---------------- xn init -----------------------------------------------------
__global__ void initxn_kernel(const float* __restrict__ pm, float* __restrict__ xn) {
    int i = blockIdx.x * 256 + threadIdx.x;
    if (i >= BN) return;
    int b = i / NN, n = i - b * NN;
    xn[i] = pm[(b * HISTC + (HISTC - 1)) * NN + n];
}

// ---------------- CSR build (once per call) -----------------------------------
__global__ void hist_kernel(const int* __restrict__ eidx,
                            int* __restrict__ deg_t, int* __restrict__ deg_s) {
    int e = blockIdx.x * 256 + threadIdx.x;
    if (e >= EE) return;
    atomicAdd(&deg_s[eidx[e]], 1);
    atomicAdd(&deg_t[eidx[EE + e]], 1);
}

__global__ __launch_bounds__(1024) void scan_kernel(
    const int* __restrict__ deg_t, const int* __restrict__ deg_s,
    int* __restrict__ off_t, int* __restrict__ off_s,
    int* __restrict__ cnt_t, int* __restrict__ cnt_s)
{
    __shared__ int pt[1024], ps[1024];
    int tid = threadIdx.x;
    int base = tid * 10;
    int st = 0, ss = 0;
    for (int k = 0; k < 10; k++) {
        int i = base + k;
        if (i < NN) { st += deg_t[i]; ss += deg_s[i]; }
    }
    pt[tid] = st; ps[tid] = ss;
    __syncthreads();
    for (int off = 1; off < 1024; off <<= 1) {
        int vt = (tid >= off) ? pt[tid - off] : 0;
        int vs = (tid >= off) ? ps[tid - off] : 0;
        __syncthreads();
        pt[tid] += vt; ps[tid] += vs;
        __syncthreads();
    }
    int ext = (tid == 0) ? 0 : pt[tid - 1];
    int exs = (tid == 0) ? 0 : ps[tid - 1];
    for (int k = 0; k < 10; k++) {
        int i = base + k;
        if (i < NN) {
            off_t[i] = ext; cnt_t[i] = ext;
            off_s[i] = exs; cnt_s[i] = exs;
            ext += deg_t[i]; exs += deg_s[i];
        }
    }
    if (tid == 0) { off_t[NN] = EE; off_s[NN] = EE; }
}

__global__ void fill_kernel(const int* __restrict__ eidx,
                            int* __restrict__ cnt_t, int* __restrict__ cnt_s,
                            int4* __restrict__ epos)
{
    int e = blockIdx.x * 256 + threadIdx.x;
    if (e >= EE) return;
    int s = eidx[e];
    int g = eidx[EE + e];
    int pt = atomicAdd(&cnt_t[g], 1);
    int ps = atomicAdd(&cnt_s[s], 1);
    int4 r; r.x = s; r.y = g; r.z = pt; r.w = ps;
    epos[e] = r;
}

// permute into tgt-slot order: eT[slot]={src,tgt,pos_s}; epreT[slot]=epre4[e]
__global__ void perm_kernel(const int4* __restrict__ epos,
                            const float4* __restrict__ epre4,
                            int4* __restrict__ eT, float4* __restrict__ epreT)
{
    int e = blockIdx.x * 256 + threadIdx.x;
    if (e >= EE) return;
    int4 p = epos[e];
    int slot = p.z;
    int4 r; r.x = p.x; r.y = p.y; r.z = p.w; r.w = 0;
    eT[slot] = r;
    epreT[slot] = epre4[e];
}

// ---------------- per-step node precompute (fp16 tables) + xn/out finalize ----
__global__ __launch_bounds__(256) void pre_kernel(
    float* __restrict__ xncur, const float* __restrict__ feature, int t,
    const float* __restrict__ xp,      // [4][BN] fc partials from node_kernel
    const float* __restrict__ fb,
    const float* __restrict__ ew1,
    const float* __restrict__ wmean, const float* __restrict__ wstd,
    __half* __restrict__ preS, __half* __restrict__ preT,
    float2* __restrict__ wind2, float* __restrict__ out)
{
    __shared__ alignas(16) float w1s[18 * EHID];
    for (int i = threadIdx.x; i < 18 * EHID; i += 256) w1s[i] = ew1[i];
    __syncthreads();
    int idx = blockIdx.x * 256 + threadIdx.x;
    if (idx >= BN * 8) return;
    int i = idx >> 3;
    int c = idx & 7;
    int b = i / NN, n = i - b * NN;
    float x0;
    if (t == 0) {
        x0 = xncur[i];
    } else {
        x0 = (xp[i] + xp[BN + i]) + (xp[2 * BN + i] + xp[3 * BN + i]) + fb[0];
        if (c == 0) {
            xncur[i] = x0;
            out[(size_t)i * PREDC + (t - 1)] = x0;
        }
    }
    float x[9];
    x[0] = x0;
    {
        const float4* fp = reinterpret_cast<const float4*>(
            feature + (((size_t)b * TSTEP + HISTC + t) * NN + n) * FEX);
        float4 u = fp[0], v = fp[1];
        x[1] = u.x; x[2] = u.y; x[3] = u.z; x[4] = u.w;
        x[5] = v.x; x[6] = v.y; x[7] = v.z; x[8] = v.w;
    }
    float4 aS = {0.f, 0.f, 0.f, 0.f}, aT = {0.f, 0.f, 0.f, 0.f};
    #pragma unroll
    for (int k = 0; k < 9; k++) {
        float4 wS = reinterpret_cast<const float4*>(&w1s[k * EHID])[c];
        float4 wT = reinterpret_cast<const float4*>(&w1s[(9 + k) * EHID])[c];
        aS.x += x[k] * wS.x; aS.y += x[k] * wS.y; aS.z += x[k] * wS.z; aS.w += x[k] * wS.w;
        aT.x += x[k] * wT.x; aT.y += x[k] * wT.y; aT.z += x[k] * wT.z; aT.w += x[k] * wT.w;
    }
    union { uint2 u; __half h[4]; } sv, tv;
    sv.h[0] = __float2half(aS.x); sv.h[1] = __float2half(aS.y);
    sv.h[2] = __float2half(aS.z); sv.h[3] = __float2half(aS.w);
    tv.h[0] = __float2half(aT.x); tv.h[1] = __float2half(aT.y);
    tv.h[2] = __float2half(aT.z); tv.h[3] = __float2half(aT.w);
    reinterpret_cast<uint2*>(preS + (size_t)i * EHID)[c] = sv.u;
    reinterpret_cast<uint2*>(preT + (size_t)i * EHID)[c] = tv.u;
    if (c == 1) {
        float sd0 = fmaxf(wstd[0], 1e-6f), sd1 = fmaxf(wstd[1], 1e-6f);
        float speed = fmaxf(x[7] * sd0 + wmean[0], 0.f);
        float wdir  = (x[8] * sd1 + wmean[1]) * 0.017453292519943295f;
        float2 wv; wv.x = 3.0f * speed; wv.y = wdir;
        wind2[i] = wv;
    }
}

__global__ __launch_bounds__(256) void finalout_kernel(
    const float* __restrict__ xp, const float* __restrict__ fb,
    float* __restrict__ out)
{
    int i = blockIdx.x * 256 + threadIdx.x;
    if (i >= BN) return;
    out[(size_t)i * PREDC + (PREDC - 1)] =
        (xp[i] + xp[BN + i]) + (xp[2 * BN + i] + xp[3 * BN + i]) + fb[0];
}

// ---------------- edge MLP, tgt-slot order, batches (2y,2y+1) interleaved -----
// h3 layout: [slot][4 batches][16 halves] -> each thread writes one 64 B
// contiguous chunk per buffer (batches 2y,2y+1 adjacent).
__global__ __launch_bounds__(256) void edge_kernel(
    const int4* __restrict__ eT, const float4* __restrict__ epreT,
    const __half* __restrict__ preS, const __half* __restrict__ preT,
    const float2* __restrict__ wind2,
    const float* __restrict__ ew1, const float* __restrict__ eb1,
    const WPack* __restrict__ wpack,
    __half* __restrict__ h3t, __half* __restrict__ h3s)
{
    int i = blockIdx.x * 256 + threadIdx.x;   // slot (EE == 625*256, no tail)
    int bA = blockIdx.y * 2;
    int bB = bA + 1;
    int4 et = eT[i];
    int s = et.x, g = et.y, ps = et.z;
    float4 ep = epreT[i];          // {ean0, ean1, 1/dist, direc}

    size_t iSA = (size_t)bA * NN + s, iTA = (size_t)bA * NN + g;
    size_t iSB = (size_t)bB * NN + s, iTB = (size_t)bB * NN + g;
    float2 wA = wind2[iSA];
    float2 wB = wind2[iSB];
    v2f ew;
    ew.x = fmaxf(wA.x * __cosf(fabsf(ep.w - wA.y)) * ep.z, 0.f);
    ew.y = fmaxf(wB.x * __cosf(fabsf(ep.w - wB.y)) * ep.z, 0.f);

    union alignas(16) { uint4 u[4]; __half2 h2[16]; } RSA, RTA, RSB, RTB;
    {
        const uint4* p;
        p = reinterpret_cast<const uint4*>(preS + iSA * EHID);
        RSA.u[0] = p[0]; RSA.u[1] = p[1]; RSA.u[2] = p[2]; RSA.u[3] = p[3];
        p = reinterpret_cast<const uint4*>(preT + iTA * EHID);
        RTA.u[0] = p[0]; RTA.u[1] = p[1]; RTA.u[2] = p[2]; RTA.u[3] = p[3];
        p = reinterpret_cast<const uint4*>(preS + iSB * EHID);
        RSB.u[0] = p[0]; RSB.u[1] = p[1]; RSB.u[2] = p[2]; RSB.u[3] = p[3];
        p = reinterpret_cast<const uint4*>(preT + iTB * EHID);
        RTB.u[0] = p[0]; RTB.u[1] = p[1]; RTB.u[2] = p[2]; RTB.u[3] = p[3];
    }

    // layer 1 — shared base term computed once for both batches
    const v2f* W18 = reinterpret_cast<const v2f*>(ew1 + 18 * EHID);
    const v2f* W19 = reinterpret_cast<const v2f*>(ew1 + 19 * EHID);
    const v2f* W20 = reinterpret_cast<const v2f*>(ew1 + 20 * EHID);
    const v2f* B1  = reinterpret_cast<const v2f*>(eb1);
    float ean0 = ep.x, ean1 = ep.y;
    __half2 h1A[16], h1B[16];
    #pragma unroll
    for (int q = 0; q < 16; q++) {
        v2f base = W18[q] * ean0 + W19[q] * ean1 + B1[q];
        v2f w20q = W20[q];
        float2 rsA = __half22float2(RSA.h2[q]);
        float2 rtA = __half22float2(RTA.h2[q]);
        float2 rsB = __half22float2(RSB.h2[q]);
        float2 rtB = __half22float2(RTB.h2[q]);
        v2f uA, uB;
        uA.x = base.x + rsA.x + rtA.x + w20q.x * ew.x;
        uA.y = base.y + rsA.y + rtA.y + w20q.y * ew.x;
        uB.x = base.x + rsB.x + rtB.x + w20q.x * ew.y;
        uB.y = base.y + rsB.y + rtB.y + w20q.y * ew.y;
        v2f sA = sigm2(uA), sB = sigm2(uB);
        h1A[q] = __floats2half2_rn(sA.x, sA.y);
        h1B[q] = __floats2half2_rn(sB.x, sB.y);
    }

    // layers 2+3 — 4 independent dot2 chains (even/odd q × batch) per output
    v2f h3ab[GOUTC];
    #pragma unroll
    for (int j = 0; j < GOUTC; j++) { h3ab[j].x = 0.f; h3ab[j].y = 0.f; }
    for (int o = 0; o < EOUTC; o++) {
        const WPack* W = wpack + o;
        float accA0 = W->b2, accA1 = 0.f;
        float accB0 = W->b2, accB1 = 0.f;
        #pragma unroll
        for (int q = 0; q < 16; q += 2) {
            __half2 w0 = W->w[q], w1 = W->w[q + 1];
            accA0 = dot2(h1A[q],     w0, accA0);
            accB0 = dot2(h1B[q],     w0, accB0);
            accA1 = dot2(h1A[q + 1], w1, accA1);
            accB1 = dot2(h1B[q + 1], w1, accB1);
        }
        v2f h2ab; h2ab.x = sigm(accA0 + accA1); h2ab.y = sigm(accB0 + accB1);
        #pragma unroll
        for (int j = 0; j < GOUTC; j++) h3ab[j] += W->nw[j] * h2ab;
    }

    // 64 B contiguous chunk: [rA(32B) | rB(32B)] at base + 32*blockIdx.y halves
    union alignas(16) { uint4 u[4]; __half h[32]; } r;
    #pragma unroll
    for (int j = 0; j < GOUTC; j++) {
        r.h[j]      = __float2half(h3ab[j].x);
        r.h[16 + j] = __float2half(h3ab[j].y);
    }
    #pragma unroll
    for (int j = GOUTC; j < 16; j++) { r.h[j] = __float2half(0.f); r.h[16 + j] = __float2half(0.f); }
    {
        __half* oT = h3t + (size_t)i * 64 + blockIdx.y * 32;   // slot-dense
        reinterpret_cast<uint4*>(oT)[0] = r.u[0];
        reinterpret_cast<uint4*>(oT)[1] = r.u[1];
        reinterpret_cast<uint4*>(oT)[2] = r.u[2];
        reinterpret_cast<uint4*>(oT)[3] = r.u[3];
        __half* oS = h3s + (size_t)ps * 64 + blockIdx.y * 32;  // scattered 64 B
        reinterpret_cast<uint4*>(oS)[0] = r.u[0];
        reinterpret_cast<uint4*>(oS)[1] = r.u[1];
        reinterpret_cast<uint4*>(oS)[2] = r.u[2];
        reinterpret_cast<uint4*>(oS)[3] = r.u[3];
    }
}

// ---------------- gather (dense reads; lane = b*16+ch maps to slot*64+lane) ---
__global__ __launch_bounds__(256) void gather_kernel(
    const __half* __restrict__ h3t, const __half* __restrict__ h3s,
    const int* __restrict__ off_t, const int* __restrict__ off_s,
    float* __restrict__ agg)
{
    int n = (blockIdx.x * 256 + threadIdx.x) >> 6;
    if (n >= NN) return;
    n = __builtin_amdgcn_readfirstlane(n);
    int lane = threadIdx.x & 63;
    int b = lane >> 4, ch = lane & 15;
    const __half* ht = h3t + lane;
    const __half* hs = h3s + lane;
    float a0 = 0.f, a1 = 0.f, a2 = 0.f, a3 = 0.f;
    {
        int i0 = off_t[n], i1 = off_t[n + 1];
        int i = i0;
        for (; i + 4 <= i1; i += 4) {
            a0 += __half2float(ht[(size_t)(i + 0) * 64]);
            a1 += __half2float(ht[(size_t)(i + 1) * 64]);
            a2 += __half2float(ht[(size_t)(i + 2) * 64]);
            a3 += __half2float(ht[(size_t)(i + 3) * 64]);
        }
        for (; i < i1; i++) a0 += __half2float(ht[(size_t)i * 64]);
    }
    {
        int i0 = off_s[n], i1 = off_s[n + 1];
        int i = i0;
        for (; i + 4 <= i1; i += 4) {
            a0 -= __half2float(hs[(size_t)(i + 0) * 64]);
            a1 -= __half2float(hs[(size_t)(i + 1) * 64]);
            a2 -= __half2float(hs[(size_t)(i + 2) * 64]);
            a3 -= __half2float(hs[(size_t)(i + 3) * 64]);
        }
        for (; i < i1; i++) a0 -= __half2float(hs[(size_t)i * 64]);
    }
    agg[((size_t)b * NN + n) * 16 + ch] = (a0 + a1) + (a2 + a3);
}

// ---------------- node: gnn-out + GRU (fp16 dot2) + fc partial ----------------
// grid (BN/64, 4); wave w of block (.,jb) handles dims [jb*16 + w*4, +4).
__global__ __launch_bounds__(256) void node_kernel(
    const float* __restrict__ xncur, const float* __restrict__ feature, int t,
    const float* __restrict__ agg, const float* __restrict__ nb,
    const __half* __restrict__ wi_h, const __half* __restrict__ wh_h,
    const float* __restrict__ bi, const float* __restrict__ bh,
    const float* __restrict__ fw,
    const __half2* __restrict__ hnold, __half2* __restrict__ hnnew,
    float* __restrict__ xp)
{
    __shared__ float xpart[4][64];
    int lane = threadIdx.x & 63;
    int wav  = threadIdx.x >> 6;
    int jb   = blockIdx.y;
    int node = blockIdx.x * 64 + lane;
    int b = node / NN;
    int n = node - b * NN;

    float xc[GINC];
    {
        const float4* ar = reinterpret_cast<const float4*>(agg + (size_t)node * 16);
        float4 a0 = ar[0], a1 = ar[1], a2 = ar[2];
        float a3 = agg[(size_t)node * 16 + 12];
        xc[0] = sigm(a0.x + nb[0]);  xc[1] = sigm(a0.y + nb[1]);
        xc[2] = sigm(a0.z + nb[2]);  xc[3] = sigm(a0.w + nb[3]);
        xc[4] = sigm(a1.x + nb[4]);  xc[5] = sigm(a1.y + nb[5]);
        xc[6] = sigm(a1.z + nb[6]);  xc[7] = sigm(a1.w + nb[7]);
        xc[8] = sigm(a2.x + nb[8]);  xc[9] = sigm(a2.y + nb[9]);
        xc[10] = sigm(a2.z + nb[10]); xc[11] = sigm(a2.w + nb[11]);
        xc[12] = sigm(a3 + nb[12]);
    }
    xc[13] = xncur[node];
    {
        const float4* fp = reinterpret_cast<const float4*>(
            feature + (((size_t)b * TSTEP + HISTC + t) * NN + n) * FEX);
        float4 u = fp[0], v = fp[1];
        xc[14] = u.x; xc[15] = u.y; xc[16] = u.z; xc[17] = u.w;
        xc[18] = v.x; xc[19] = v.y; xc[20] = v.z; xc[21] = v.w;
    }
    __half2 xch[11];
    #pragma unroll
    for (int p = 0; p < 11; p++) xch[p] = __floats2half2_rn(xc[2*p], xc[2*p+1]);

    __half2 hh[32];
    #pragma unroll
    for (int p = 0; p < 32; p++) hh[p] = hnold[(size_t)p * BN + node];

    float xsum = 0.f;
    #pragma unroll
    for (int jj2 = 0; jj2 < 2; jj2++) {
        int j0 = __builtin_amdgcn_readfirstlane(jb * 16 + wav * 4 + jj2 * 2);
        union { __half2 h; __half v[2]; } holdw;
        holdw.h = hnold[(size_t)(j0 >> 1) * BN + node];
        float hnew2[2];
        #pragma unroll
        for (int d = 0; d < 2; d++) {
            int j = j0 + d;
            float ir = bi[j], iz = bi[64 + j], in_ = bi[128 + j];
            const __half2* wr0 = reinterpret_cast<const __half2*>(wi_h + (size_t)j * GINC);
            const __half2* wr1 = reinterpret_cast<const __half2*>(wi_h + (size_t)(64 + j) * GINC);
            const __half2* wr2 = reinterpret_cast<const __half2*>(wi_h + (size_t)(128 + j) * GINC);
            #pragma unroll
            for (int p = 0; p < 11; p++) {
                ir  = dot2(xch[p], wr0[p], ir);
                iz  = dot2(xch[p], wr1[p], iz);
                in_ = dot2(xch[p], wr2[p], in_);
            }
            float hr0 = bh[j], hz0 = bh[64 + j], hn0 = bh[128 + j];
            float hr1 = 0.f, hz1 = 0.f, hn1 = 0.f;
            const __half2* vr0 = reinterpret_cast<const __half2*>(wh_h + (size_t)j * HIDC);
            const __half2* vr1 = reinterpret_cast<const __half2*>(wh_h + (size_t)(64 + j) * HIDC);
            const __half2* vr2 = reinterpret_cast<const __half2*>(wh_h + (size_t)(128 + j) * HIDC);
            #pragma unroll
            for (int p = 0; p < 32; p += 2) {
                hr0 = dot2(hh[p],     vr0[p],     hr0);
                hz0 = dot2(hh[p],     vr1[p],     hz0);
                hn0 = dot2(hh[p],     vr2[p],     hn0);
                hr1 = dot2(hh[p + 1], vr0[p + 1], hr1);
                hz1 = dot2(hh[p + 1], vr1[p + 1], hz1);
                hn1 = dot2(hh[p + 1], vr2[p + 1], hn1);
            }
            float r  = sigm(ir + hr0 + hr1);
            float z  = sigm(iz + hz0 + hz1);
            float nn = tanh_fast(in_ + r * (hn0 + hn1));
            float hold = __half2float(holdw.v[d]);
            float hnew = (1.f - z) * nn + z * hold;
            hnew2[d] = hnew;
            xsum += hnew * fw[j];
        }
        hnnew[(size_t)(j0 >> 1) * BN + node] = __floats2half2_rn(hnew2[0], hnew2[1]);
    }
    xpart[wav][lane] = xsum;
    __syncthreads();
    if (wav == 0) {
        float tot = xpart[0][lane] + xpart[1][lane] + xpart[2][lane] + xpart[3][lane];
        xp[(size_t)jb * BN + node] = tot;
    }
}

extern "C" void kernel_launch(void* const* d_in, const int* in_sizes, int n_in,
                              void* d_out, int out_size, void* d_ws, size_t ws_size,
                              hipStream_t stream)
{
    const float* pm    = (const float*)d_in[0];
    const float* feat  = (const float*)d_in[1];
    const float* ea    = (const float*)d_in[2];
    const float* wmean = (const float*)d_in[3];
    const float* wstd  = (const float*)d_in[4];
    const float* ew1   = (const float*)d_in[5];
    const float* eb1   = (const float*)d_in[6];
    const float* ew2   = (const float*)d_in[7];
    const float* eb2   = (const float*)d_in[8];
    const float* nw    = (const float*)d_in[9];
    const float* nb    = (const float*)d_in[10];
    const float* wi    = (const float*)d_in[11];
    const float* wh    = (const float*)d_in[12];
    const float* bi    = (const float*)d_in[13];
    const float* bh    = (const float*)d_in[14];
    const float* fw    = (const float*)d_in[15];
    const float* fb    = (const float*)d_in[16];
    const int*   eidx  = (const int*)d_in[17];
    float* out = (float*)d_out;

    char* w = (char*)d_ws;
    double* partd = (double*)w;                    w += 256 * 4 * sizeof(double);
    float*  stats = (float*)w;                     w += 16 * sizeof(float);
    WPack*  wpack = (WPack*)w;                     w += EOUTC * sizeof(WPack);
    float4* epre4 = (float4*)w;                    w += (size_t)EE * sizeof(float4);
    float4* epreT = (float4*)w;                    w += (size_t)EE * sizeof(float4);
    float*  xncur = (float*)w;                     w += (size_t)BN * sizeof(float);
    float*  xp    = (float*)w;                     w += (size_t)4 * BN * sizeof(float);
    __half2* hnA  = (__half2*)w;                   w += (size_t)32 * BN * sizeof(__half2);
    __half2* hnB  = (__half2*)w;                   w += (size_t)32 * BN * sizeof(__half2);
    float*  agg13 = (float*)w;                     w += (size_t)BN * 16 * sizeof(float);
    __half* preS  = (__half*)w;                    w += (size_t)BN * EHID * sizeof(__half);
    __half* preT  = (__half*)w;                    w += (size_t)BN * EHID * sizeof(__half);
    float2* wind2 = (float2*)w;                    w += (size_t)BN * sizeof(float2);
    __half* h3t   = (__half*)w;                    w += (size_t)EE * 64 * sizeof(__half);
    __half* h3s   = (__half*)w;                    w += (size_t)EE * 64 * sizeof(__half);
    __half* wi_h  = (__half*)w;                    w += (size_t)192 * GINC * sizeof(__half);
    __half* wh_h  = (__half*)w;                    w += (size_t)192 * HIDC * sizeof(__half);
    int*    deg_t = (int*)w;                       w += NN * sizeof(int);
    int*    deg_s = (int*)w;                       w += NN * sizeof(int);
    int*    off_t = (int*)w;                       w += (NN + 1) * sizeof(int);
    int*    off_s = (int*)w;                       w += (NN + 1) * sizeof(int);
    int*    cnt_t = (int*)w;                       w += NN * sizeof(int);
    int*    cnt_s = (int*)w;                       w += NN * sizeof(int);
    int4*   epos  = (int4*)w;                      w += (size_t)EE * sizeof(int4);
    int4*   eT    = (int4*)w;                      w += (size_t)EE * sizeof(int4);

    stats1_kernel<<<256, 256, 0, stream>>>(ea, partd);
    stats2_kernel<<<1, 256, 0, stream>>>(partd, stats);
    edgepre_kernel<<<(EE + 255) / 256, 256, 0, stream>>>(ea, stats, epre4);
    cvtw_kernel<<<(192 * HIDC + 255) / 256, 256, 0, stream>>>(
        wi, wh, ew2, eb2, nw, wi_h, wh_h, wpack);
    initxn_kernel<<<(BN + 255) / 256, 256, 0, stream>>>(pm, xncur);
    hipMemsetAsync(hnA, 0, (size_t)32 * BN * sizeof(__half2), stream);
    hipMemsetAsync(deg_t, 0, 2 * NN * sizeof(int), stream);
    hist_kernel<<<(EE + 255) / 256, 256, 0, stream>>>(eidx, deg_t, deg_s);
    scan_kernel<<<1, 1024, 0, stream>>>(deg_t, deg_s, off_t, off_s, cnt_t, cnt_s);
    fill_kernel<<<(EE + 255) / 256, 256, 0, stream>>>(eidx, cnt_t, cnt_s, epos);
    perm_kernel<<<(EE + 255) / 256, 256, 0, stream>>>(epos, epre4, eT, epreT);

    for (int t = 0; t < PREDC; t++) {
        const __half2* hnold = (t & 1) ? hnB : hnA;
        __half2*       hnnew = (t & 1) ? hnA : hnB;
        pre_kernel<<<(BN * 8 + 255) / 256, 256, 0, stream>>>(
            xncur, feat, t, xp, fb, ew1, wmean, wstd, preS, preT, wind2, out);
        edge_kernel<<<dim3(EE / 256, 2), 256, 0, stream>>>(
            eT, epreT, preS, preT, wind2, ew1, eb1, wpack, h3t, h3s);
        gather_kernel<<<(NN * 64 + 255) / 256, 256, 0, stream>>>(
            h3t, h3s, off_t, off_s, agg13);
        node_kernel<<<dim3(BN / 64, 4), 256, 0, stream>>>(
            xncur, feat, t, agg13, nb, wi_h, wh_h, bi, bh, fw, hnold, hnnew, xp);
    }
    finalout_kernel<<<(BN + 255) / 256, 256, 0, stream>>>(xp, fb, out);
}

// Round 15
// 1040.935 us; speedup vs baseline: 1.0539x; 1.0539x over previous
//
#include <hip/hip_runtime.h>
#include <hip/hip_fp16.h>
#include <cstddef>

#define BB    4
#define NN    10000
#define EE    160000
#define BN    40000      // BB*NN
#define HISTC 8
#define PREDC 12
#define TSTEP 20         // HIST+PRED
#define FEX   8
#define HIDC  64
#define EHID  32
#define EOUTC 30
#define GOUTC 13
#define GINC  22         // GOUTC + 9

typedef float v2f __attribute__((ext_vector_type(2)));
typedef _Float16 v2h __attribute__((ext_vector_type(2)));

struct alignas(16) WPack {      // 128 B: one layer-2 output channel
    __half2 w[16];   // w2 row (32 halves)
    float   nw[14];  // folded n_w row (13 + pad)
    float   b2;
    float   pad;
};

__device__ __forceinline__ float fast_rcp(float x) { return __builtin_amdgcn_rcpf(x); }
__device__ __forceinline__ float sigm(float x) {
    return fast_rcp(1.0f + __expf(-x));
}
__device__ __forceinline__ v2f sigm2(v2f x) {
    v2f r; r.x = sigm(x.x); r.y = sigm(x.y); return r;
}
__device__ __forceinline__ float tanh_fast(float x) {
    x = fminf(fmaxf(x, -15.0f), 15.0f);
    float e = __expf(2.0f * x);
    return (e - 1.0f) * fast_rcp(e + 1.0f);
}

__device__ __forceinline__ float dot2(__half2 a, __half2 b, float c) {
#if __has_builtin(__builtin_amdgcn_fdot2)
    union { __half2 h; v2h v; } ua, ub;
    ua.h = a; ub.h = b;
    return __builtin_amdgcn_fdot2(ua.v, ub.v, c, false);
#else
    float2 fa = __half22float2(a), fb = __half22float2(b);
    return c + fa.x * fb.x + fa.y * fb.y;
#endif
}

// ---------------- edge_attr stats ---------------------------------------------
__global__ __launch_bounds__(256) void stats1_kernel(const float* __restrict__ ea,
                                                     double* __restrict__ part) {
    __shared__ double sm[256][4];
    int tid = threadIdx.x;
    double s0 = 0, s1 = 0, q0 = 0, q1 = 0;
    for (int e = blockIdx.x * 256 + tid; e < EE; e += 256 * 256) {
        float2 v = reinterpret_cast<const float2*>(ea)[e];
        double v0 = (double)v.x, v1 = (double)v.y;
        s0 += v0; q0 += v0 * v0;
        s1 += v1; q1 += v1 * v1;
    }
    sm[tid][0] = s0; sm[tid][1] = s1; sm[tid][2] = q0; sm[tid][3] = q1;
    __syncthreads();
    for (int off = 128; off > 0; off >>= 1) {
        if (tid < off)
            for (int k = 0; k < 4; k++) sm[tid][k] += sm[tid + off][k];
        __syncthreads();
    }
    if (tid == 0) {
        part[blockIdx.x * 4 + 0] = sm[0][0];
        part[blockIdx.x * 4 + 1] = sm[0][1];
        part[blockIdx.x * 4 + 2] = sm[0][2];
        part[blockIdx.x * 4 + 3] = sm[0][3];
    }
}

__global__ __launch_bounds__(256) void stats2_kernel(const double* __restrict__ part,
                                                     float* __restrict__ stats) {
    __shared__ double sm[256][4];
    int tid = threadIdx.x;
    sm[tid][0] = part[tid * 4 + 0];
    sm[tid][1] = part[tid * 4 + 1];
    sm[tid][2] = part[tid * 4 + 2];
    sm[tid][3] = part[tid * 4 + 3];
    __syncthreads();
    for (int off = 128; off > 0; off >>= 1) {
        if (tid < off)
            for (int k = 0; k < 4; k++) sm[tid][k] += sm[tid + off][k];
        __syncthreads();
    }
    if (tid == 0) {
        double m0 = sm[0][0] / EE, m1 = sm[0][1] / EE;
        double v0 = (sm[0][2] - sm[0][0] * sm[0][0] / EE) / (double)(EE - 1);
        double v1 = (sm[0][3] - sm[0][1] * sm[0][1] / EE) / (double)(EE - 1);
        float sd0 = fmaxf((float)sqrt(v0 > 0 ? v0 : 0.0), 1e-6f);
        float sd1 = fmaxf((float)sqrt(v1 > 0 ? v1 : 0.0), 1e-6f);
        stats[0] = (float)m0; stats[1] = (float)m1;
        stats[2] = 1.0f / sd0; stats[3] = 1.0f / sd1;
    }
}

// ---------------- per-edge precompute -----------------------------------------
__global__ __launch_bounds__(256) void edgepre_kernel(
    const float* __restrict__ ea, const float* __restrict__ stats,
    float4* __restrict__ epre4)
{
    int e = blockIdx.x * 256 + threadIdx.x;
    if (e >= EE) return;
    float2 v = reinterpret_cast<const float2*>(ea)[e];
    float4 r;
    r.x = (v.x - stats[0]) * stats[2];
    r.y = (v.y - stats[1]) * stats[3];
    r.z = 1.0f / fmaxf(v.x, 1e-3f);
    r.w = v.y;
    epre4[e] = r;
}

// ---------------- weight conversion + WPack build (once per call) -------------
__global__ __launch_bounds__(256) void cvtw_kernel(
    const float* __restrict__ wi, const float* __restrict__ wh,
    const float* __restrict__ ew2, const float* __restrict__ eb2,
    const float* __restrict__ nw,
    __half* __restrict__ wi_h, __half* __restrict__ wh_h,
    WPack* __restrict__ wpack)
{
    int i = blockIdx.x * 256 + threadIdx.x;
    if (i < 192 * GINC) wi_h[i] = __float2half(wi[i]);
    if (i < 192 * HIDC) wh_h[i] = __float2half(wh[i]);
    if (i < EOUTC) {
        WPack wp;
        #pragma unroll
        for (int q = 0; q < 16; q++)
            wp.w[q] = __floats2half2_rn(ew2[(2 * q) * EOUTC + i],
                                        ew2[(2 * q + 1) * EOUTC + i]);
        #pragma unroll
        for (int j = 0; j < GOUTC; j++) wp.nw[j] = nw[i * GOUTC + j];
        wp.nw[13] = 0.f;
        wp.b2 = eb2[i];
        wp.pad = 0.f;
        wpack[i] = wp;
    }
}

// ---------------- xn init -----------------------------------------------------
__global__ void initxn_kernel(const float* __restrict__ pm, float* __restrict__ xn) {
    int i = blockIdx.x * 256 + threadIdx.x;
    if (i >= BN) return;
    int b = i / NN, n = i - b * NN;
    xn[i] = pm[(b * HISTC + (HISTC - 1)) * NN + n];
}

// ---------------- CSR build (once per call) -----------------------------------
__global__ void hist_kernel(const int* __restrict__ eidx,
                            int* __restrict__ deg_t, int* __restrict__ deg_s) {
    int e = blockIdx.x * 256 + threadIdx.x;
    if (e >= EE) return;
    atomicAdd(&deg_s[eidx[e]], 1);
    atomicAdd(&deg_t[eidx[EE + e]], 1);
}

__global__ __launch_bounds__(1024) void scan_kernel(
    const int* __restrict__ deg_t, const int* __restrict__ deg_s,
    int* __restrict__ off_t, int* __restrict__ off_s,
    int* __restrict__ cnt_t, int* __restrict__ cnt_s)
{
    __shared__ int pt[1024], ps[1024];
    int tid = threadIdx.x;
    int base = tid * 10;
    int st = 0, ss = 0;
    for (int k = 0; k < 10; k++) {
        int i = base + k;
        if (i < NN) { st += deg_t[i]; ss += deg_s[i]; }
    }
    pt[tid] = st; ps[tid] = ss;
    __syncthreads();
    for (int off = 1; off < 1024; off <<= 1) {
        int vt = (tid >= off) ? pt[tid - off] : 0;
        int vs = (tid >= off) ? ps[tid - off] : 0;
        __syncthreads();
        pt[tid] += vt; ps[tid] += vs;
        __syncthreads();
    }
    int ext = (tid == 0) ? 0 : pt[tid - 1];
    int exs = (tid == 0) ? 0 : ps[tid - 1];
    for (int k = 0; k < 10; k++) {
        int i = base + k;
        if (i < NN) {
            off_t[i] = ext; cnt_t[i] = ext;
            off_s[i] = exs; cnt_s[i] = exs;
            ext += deg_t[i]; exs += deg_s[i];
        }
    }
    if (tid == 0) { off_t[NN] = EE; off_s[NN] = EE; }
}

__global__ void fill_kernel(const int* __restrict__ eidx,
                            int* __restrict__ cnt_t, int* __restrict__ cnt_s,
                            int4* __restrict__ epos)
{
    int e = blockIdx.x * 256 + threadIdx.x;
    if (e >= EE) return;
    int s = eidx[e];
    int g = eidx[EE + e];
    int pt = atomicAdd(&cnt_t[g], 1);
    int ps = atomicAdd(&cnt_s[s], 1);
    int4 r; r.x = s; r.y = g; r.z = pt; r.w = ps;
    epos[e] = r;
}

// permute into tgt-slot order: eT[slot]={src,tgt,pos_s}; epreT[slot]=epre4[e]
__global__ void perm_kernel(const int4* __restrict__ epos,
                            const float4* __restrict__ epre4,
                            int4* __restrict__ eT, float4* __restrict__ epreT)
{
    int e = blockIdx.x * 256 + threadIdx.x;
    if (e >= EE) return;
    int4 p = epos[e];
    int slot = p.z;
    int4 r; r.x = p.x; r.y = p.y; r.z = p.w; r.w = 0;
    eT[slot] = r;
    epreT[slot] = epre4[e];
}

// ---------------- per-step node precompute (fp16 tables) + xn/out finalize ----
__global__ __launch_bounds__(256) void pre_kernel(
    float* __restrict__ xncur, const float* __restrict__ feature, int t,
    const float* __restrict__ xp,      // [4][BN] fc partials from node_kernel
    const float* __restrict__ fb,
    const float* __restrict__ ew1,
    const float* __restrict__ wmean, const float* __restrict__ wstd,
    __half* __restrict__ preS, __half* __restrict__ preT,
    float2* __restrict__ wind2, float* __restrict__ out)
{
    __shared__ alignas(16) float w1s[18 * EHID];
    for (int i = threadIdx.x; i < 18 * EHID; i += 256) w1s[i] = ew1[i];
    __syncthreads();
    int idx = blockIdx.x * 256 + threadIdx.x;
    if (idx >= BN * 8) return;
    int i = idx >> 3;
    int c = idx & 7;
    int b = i / NN, n = i - b * NN;
    float x0;
    if (t == 0) {
        x0 = xncur[i];
    } else {
        x0 = (xp[i] + xp[BN + i]) + (xp[2 * BN + i] + xp[3 * BN + i]) + fb[0];
        if (c == 0) {
            xncur[i] = x0;
            out[(size_t)i * PREDC + (t - 1)] = x0;
        }
    }
    float x[9];
    x[0] = x0;
    {
        const float4* fp = reinterpret_cast<const float4*>(
            feature + (((size_t)b * TSTEP + HISTC + t) * NN + n) * FEX);
        float4 u = fp[0], v = fp[1];
        x[1] = u.x; x[2] = u.y; x[3] = u.z; x[4] = u.w;
        x[5] = v.x; x[6] = v.y; x[7] = v.z; x[8] = v.w;
    }
    float4 aS = {0.f, 0.f, 0.f, 0.f}, aT = {0.f, 0.f, 0.f, 0.f};
    #pragma unroll
    for (int k = 0; k < 9; k++) {
        float4 wS = reinterpret_cast<const float4*>(&w1s[k * EHID])[c];
        float4 wT = reinterpret_cast<const float4*>(&w1s[(9 + k) * EHID])[c];
        aS.x += x[k] * wS.x; aS.y += x[k] * wS.y; aS.z += x[k] * wS.z; aS.w += x[k] * wS.w;
        aT.x += x[k] * wT.x; aT.y += x[k] * wT.y; aT.z += x[k] * wT.z; aT.w += x[k] * wT.w;
    }
    union { uint2 u; __half h[4]; } sv, tv;
    sv.h[0] = __float2half(aS.x); sv.h[1] = __float2half(aS.y);
    sv.h[2] = __float2half(aS.z); sv.h[3] = __float2half(aS.w);
    tv.h[0] = __float2half(aT.x); tv.h[1] = __float2half(aT.y);
    tv.h[2] = __float2half(aT.z); tv.h[3] = __float2half(aT.w);
    reinterpret_cast<uint2*>(preS + (size_t)i * EHID)[c] = sv.u;
    reinterpret_cast<uint2*>(preT + (size_t)i * EHID)[c] = tv.u;
    if (c == 1) {
        float sd0 = fmaxf(wstd[0], 1e-6f), sd1 = fmaxf(wstd[1], 1e-6f);
        float speed = fmaxf(x[7] * sd0 + wmean[0], 0.f);
        float wdir  = (x[8] * sd1 + wmean[1]) * 0.017453292519943295f;
        float2 wv; wv.x = 3.0f * speed; wv.y = wdir;
        wind2[i] = wv;
    }
}

__global__ __launch_bounds__(256) void finalout_kernel(
    const float* __restrict__ xp, const float* __restrict__ fb,
    float* __restrict__ out)
{
    int i = blockIdx.x * 256 + threadIdx.x;
    if (i >= BN) return;
    out[(size_t)i * PREDC + (PREDC - 1)] =
        (xp[i] + xp[BN + i]) + (xp[2 * BN + i] + xp[3 * BN + i]) + fb[0];
}

// ---------------- edge MLP, tgt-slot order, 1 batch/thread, grid (625,4) ------
// High occupancy for latency hiding; weights via uniform scalar streams.
__global__ __launch_bounds__(256) void edge_kernel(
    const int4* __restrict__ eT, const float4* __restrict__ epreT,
    const __half* __restrict__ preS, const __half* __restrict__ preT,
    const float2* __restrict__ wind2,
    const float* __restrict__ ew1, const float* __restrict__ eb1,
    const WPack* __restrict__ wpack,
    __half* __restrict__ h3t, __half* __restrict__ h3s)
{
    int i = blockIdx.x * 256 + threadIdx.x;   // slot (EE == 625*256, no tail)
    int b = blockIdx.y;
    int4 et = eT[i];
    int s = et.x, g = et.y, ps = et.z;
    float4 ep = epreT[i];          // {ean0, ean1, 1/dist, direc}

    size_t iS = (size_t)b * NN + s, iT = (size_t)b * NN + g;
    float2 wv2 = wind2[iS];
    float ew = fmaxf(wv2.x * __cosf(fabsf(ep.w - wv2.y)) * ep.z, 0.f);

    union alignas(16) { uint4 u[4]; __half2 h2[16]; } RS, RT;
    {
        const uint4* p;
        p = reinterpret_cast<const uint4*>(preS + iS * EHID);
        RS.u[0] = p[0]; RS.u[1] = p[1]; RS.u[2] = p[2]; RS.u[3] = p[3];
        p = reinterpret_cast<const uint4*>(preT + iT * EHID);
        RT.u[0] = p[0]; RT.u[1] = p[1]; RT.u[2] = p[2]; RT.u[3] = p[3];
    }

    // layer 1 — weights from uniform scalar streams
    const v2f* W18 = reinterpret_cast<const v2f*>(ew1 + 18 * EHID);
    const v2f* W19 = reinterpret_cast<const v2f*>(ew1 + 19 * EHID);
    const v2f* W20 = reinterpret_cast<const v2f*>(ew1 + 20 * EHID);
    const v2f* B1  = reinterpret_cast<const v2f*>(eb1);
    float ean0 = ep.x, ean1 = ep.y;
    __half2 h1h[16];
    #pragma unroll
    for (int q = 0; q < 16; q++) {
        v2f u = W18[q] * ean0 + W19[q] * ean1 + B1[q] + W20[q] * ew;
        float2 rs = __half22float2(RS.h2[q]);
        float2 rt = __half22float2(RT.h2[q]);
        u.x += rs.x + rt.x;
        u.y += rs.y + rt.y;
        v2f sg = sigm2(u);
        h1h[q] = __floats2half2_rn(sg.x, sg.y);
    }

    // layers 2+3 — dual dot2 chains (even/odd q) per output channel
    v2f h3p[7];
    #pragma unroll
    for (int j = 0; j < 7; j++) { h3p[j].x = 0.f; h3p[j].y = 0.f; }
    for (int o = 0; o < EOUTC; o++) {
        const WPack* W = wpack + o;
        float acc0 = W->b2, acc1 = 0.f;
        #pragma unroll
        for (int q = 0; q < 16; q += 2) {
            acc0 = dot2(h1h[q],     W->w[q],     acc0);
            acc1 = dot2(h1h[q + 1], W->w[q + 1], acc1);
        }
        float h2v = sigm(acc0 + acc1);
        const v2f* nr = reinterpret_cast<const v2f*>(W->nw);
        #pragma unroll
        for (int j = 0; j < 7; j++) h3p[j] += nr[j] * h2v;
    }

    union alignas(16) { uint4 u[2]; __half2 h2[8]; } r;
    #pragma unroll
    for (int j = 0; j < 7; j++) r.h2[j] = __floats2half2_rn(h3p[j].x, h3p[j].y);
    r.h2[7] = __floats2half2_rn(0.f, 0.f);
    {
        __half* oT = h3t + ((size_t)b * EE + i) * 16;     // coalesced
        reinterpret_cast<uint4*>(oT)[0] = r.u[0];
        reinterpret_cast<uint4*>(oT)[1] = r.u[1];
        __half* oS = h3s + ((size_t)b * EE + ps) * 16;    // scattered
        reinterpret_cast<uint4*>(oS)[0] = r.u[0];
        reinterpret_cast<uint4*>(oS)[1] = r.u[1];
    }
}

// ---------------- gather (4-way unrolled for MLP) -----------------------------
__global__ __launch_bounds__(256) void gather_kernel(
    const __half* __restrict__ h3t, const __half* __restrict__ h3s,
    const int* __restrict__ off_t, const int* __restrict__ off_s,
    float* __restrict__ agg)
{
    int n = (blockIdx.x * 256 + threadIdx.x) >> 6;
    if (n >= NN) return;
    n = __builtin_amdgcn_readfirstlane(n);
    int lane = threadIdx.x & 63;
    int b = lane >> 4, ch = lane & 15;
    const __half* ht = h3t + (size_t)b * EE * 16 + ch;
    const __half* hs = h3s + (size_t)b * EE * 16 + ch;
    float a0 = 0.f, a1 = 0.f, a2 = 0.f, a3 = 0.f;
    {
        int i0 = off_t[n], i1 = off_t[n + 1];
        int i = i0;
        for (; i + 4 <= i1; i += 4) {
            a0 += __half2float(ht[(size_t)(i + 0) * 16]);
            a1 += __half2float(ht[(size_t)(i + 1) * 16]);
            a2 += __half2float(ht[(size_t)(i + 2) * 16]);
            a3 += __half2float(ht[(size_t)(i + 3) * 16]);
        }
        for (; i < i1; i++) a0 += __half2float(ht[(size_t)i * 16]);
    }
    {
        int i0 = off_s[n], i1 = off_s[n + 1];
        int i = i0;
        for (; i + 4 <= i1; i += 4) {
            a0 -= __half2float(hs[(size_t)(i + 0) * 16]);
            a1 -= __half2float(hs[(size_t)(i + 1) * 16]);
            a2 -= __half2float(hs[(size_t)(i + 2) * 16]);
            a3 -= __half2float(hs[(size_t)(i + 3) * 16]);
        }
        for (; i < i1; i++) a0 -= __half2float(hs[(size_t)i * 16]);
    }
    agg[((size_t)b * NN + n) * 16 + ch] = (a0 + a1) + (a2 + a3);
}

// ---------------- node: gnn-out + GRU (fp16 dot2) + fc partial ----------------
// grid (BN/64, 4); wave w of block (.,jb) handles dims [jb*16 + w*4, +4).
__global__ __launch_bounds__(256) void node_kernel(
    const float* __restrict__ xncur, const float* __restrict__ feature, int t,
    const float* __restrict__ agg, const float* __restrict__ nb,
    const __half* __restrict__ wi_h, const __half* __restrict__ wh_h,
    const float* __restrict__ bi, const float* __restrict__ bh,
    const float* __restrict__ fw,
    const __half2* __restrict__ hnold, __half2* __restrict__ hnnew,
    float* __restrict__ xp)
{
    __shared__ float xpart[4][64];
    int lane = threadIdx.x & 63;
    int wav  = threadIdx.x >> 6;
    int jb   = blockIdx.y;
    int node = blockIdx.x * 64 + lane;
    int b = node / NN;
    int n = node - b * NN;

    float xc[GINC];
    {
        const float4* ar = reinterpret_cast<const float4*>(agg + (size_t)node * 16);
        float4 a0 = ar[0], a1 = ar[1], a2 = ar[2];
        float a3 = agg[(size_t)node * 16 + 12];
        xc[0] = sigm(a0.x + nb[0]);  xc[1] = sigm(a0.y + nb[1]);
        xc[2] = sigm(a0.z + nb[2]);  xc[3] = sigm(a0.w + nb[3]);
        xc[4] = sigm(a1.x + nb[4]);  xc[5] = sigm(a1.y + nb[5]);
        xc[6] = sigm(a1.z + nb[6]);  xc[7] = sigm(a1.w + nb[7]);
        xc[8] = sigm(a2.x + nb[8]);  xc[9] = sigm(a2.y + nb[9]);
        xc[10] = sigm(a2.z + nb[10]); xc[11] = sigm(a2.w + nb[11]);
        xc[12] = sigm(a3 + nb[12]);
    }
    xc[13] = xncur[node];
    {
        const float4* fp = reinterpret_cast<const float4*>(
            feature + (((size_t)b * TSTEP + HISTC + t) * NN + n) * FEX);
        float4 u = fp[0], v = fp[1];
        xc[14] = u.x; xc[15] = u.y; xc[16] = u.z; xc[17] = u.w;
        xc[18] = v.x; xc[19] = v.y; xc[20] = v.z; xc[21] = v.w;
    }
    __half2 xch[11];
    #pragma unroll
    for (int p = 0; p < 11; p++) xch[p] = __floats2half2_rn(xc[2*p], xc[2*p+1]);

    __half2 hh[32];
    #pragma unroll
    for (int p = 0; p < 32; p++) hh[p] = hnold[(size_t)p * BN + node];

    float xsum = 0.f;
    #pragma unroll
    for (int jj2 = 0; jj2 < 2; jj2++) {
        int j0 = __builtin_amdgcn_readfirstlane(jb * 16 + wav * 4 + jj2 * 2);
        union { __half2 h; __half v[2]; } holdw;
        holdw.h = hnold[(size_t)(j0 >> 1) * BN + node];
        float hnew2[2];
        #pragma unroll
        for (int d = 0; d < 2; d++) {
            int j = j0 + d;
            float ir = bi[j], iz = bi[64 + j], in_ = bi[128 + j];
            const __half2* wr0 = reinterpret_cast<const __half2*>(wi_h + (size_t)j * GINC);
            const __half2* wr1 = reinterpret_cast<const __half2*>(wi_h + (size_t)(64 + j) * GINC);
            const __half2* wr2 = reinterpret_cast<const __half2*>(wi_h + (size_t)(128 + j) * GINC);
            #pragma unroll
            for (int p = 0; p < 11; p++) {
                ir  = dot2(xch[p], wr0[p], ir);
                iz  = dot2(xch[p], wr1[p], iz);
                in_ = dot2(xch[p], wr2[p], in_);
            }
            float hr0 = bh[j], hz0 = bh[64 + j], hn0 = bh[128 + j];
            float hr1 = 0.f, hz1 = 0.f, hn1 = 0.f;
            const __half2* vr0 = reinterpret_cast<const __half2*>(wh_h + (size_t)j * HIDC);
            const __half2* vr1 = reinterpret_cast<const __half2*>(wh_h + (size_t)(64 + j) * HIDC);
            const __half2* vr2 = reinterpret_cast<const __half2*>(wh_h + (size_t)(128 + j) * HIDC);
            #pragma unroll
            for (int p = 0; p < 32; p += 2) {
                hr0 = dot2(hh[p],     vr0[p],     hr0);
                hz0 = dot2(hh[p],     vr1[p],     hz0);
                hn0 = dot2(hh[p],     vr2[p],     hn0);
                hr1 = dot2(hh[p + 1], vr0[p + 1], hr1);
                hz1 = dot2(hh[p + 1], vr1[p + 1], hz1);
                hn1 = dot2(hh[p + 1], vr2[p + 1], hn1);
            }
            float r  = sigm(ir + hr0 + hr1);
            float z  = sigm(iz + hz0 + hz1);
            float nn = tanh_fast(in_ + r * (hn0 + hn1));
            float hold = __half2float(holdw.v[d]);
            float hnew = (1.f - z) * nn + z * hold;
            hnew2[d] = hnew;
            xsum += hnew * fw[j];
        }
        hnnew[(size_t)(j0 >> 1) * BN + node] = __floats2half2_rn(hnew2[0], hnew2[1]);
    }
    xpart[wav][lane] = xsum;
    __syncthreads();
    if (wav == 0) {
        float tot = xpart[0][lane] + xpart[1][lane] + xpart[2][lane] + xpart[3][lane];
        xp[(size_t)jb * BN + node] = tot;
    }
}

extern "C" void kernel_launch(void* const* d_in, const int* in_sizes, int n_in,
                              void* d_out, int out_size, void* d_ws, size_t ws_size,
                              hipStream_t stream)
{
    const float* pm    = (const float*)d_in[0];
    const float* feat  = (const float*)d_in[1];
    const float* ea    = (const float*)d_in[2];
    const float* wmean = (const float*)d_in[3];
    const float* wstd  = (const float*)d_in[4];
    const float* ew1   = (const float*)d_in[5];
    const float* eb1   = (const float*)d_in[6];
    const float* ew2   = (const float*)d_in[7];
    const float* eb2   = (const float*)d_in[8];
    const float* nw    = (const float*)d_in[9];
    const float* nb    = (const float*)d_in[10];
    const float* wi    = (const float*)d_in[11];
    const float* wh    = (const float*)d_in[12];
    const float* bi    = (const float*)d_in[13];
    const float* bh    = (const float*)d_in[14];
    const float* fw    = (const float*)d_in[15];
    const float* fb    = (const float*)d_in[16];
    const int*   eidx  = (const int*)d_in[17];
    float* out = (float*)d_out;

    char* w = (char*)d_ws;
    double* partd = (double*)w;                    w += 256 * 4 * sizeof(double);
    float*  stats = (float*)w;                     w += 16 * sizeof(float);
    WPack*  wpack = (WPack*)w;                     w += EOUTC * sizeof(WPack);
    float4* epre4 = (float4*)w;                    w += (size_t)EE * sizeof(float4);
    float4* epreT = (float4*)w;                    w += (size_t)EE * sizeof(float4);
    float*  xncur = (float*)w;                     w += (size_t)BN * sizeof(float);
    float*  xp    = (float*)w;                     w += (size_t)4 * BN * sizeof(float);
    __half2* hnA  = (__half2*)w;                   w += (size_t)32 * BN * sizeof(__half2);
    __half2* hnB  = (__half2*)w;                   w += (size_t)32 * BN * sizeof(__half2);
    float*  agg13 = (float*)w;                     w += (size_t)BN * 16 * sizeof(float);
    __half* preS  = (__half*)w;                    w += (size_t)BN * EHID * sizeof(__half);
    __half* preT  = (__half*)w;                    w += (size_t)BN * EHID * sizeof(__half);
    float2* wind2 = (float2*)w;                    w += (size_t)BN * sizeof(float2);
    __half* h3t   = (__half*)w;                    w += (size_t)BB * EE * 16 * sizeof(__half);
    __half* h3s   = (__half*)w;                    w += (size_t)BB * EE * 16 * sizeof(__half);
    __half* wi_h  = (__half*)w;                    w += (size_t)192 * GINC * sizeof(__half);
    __half* wh_h  = (__half*)w;                    w += (size_t)192 * HIDC * sizeof(__half);
    int*    deg_t = (int*)w;                       w += NN * sizeof(int);
    int*    deg_s = (int*)w;                       w += NN * sizeof(int);
    int*    off_t = (int*)w;                       w += (NN + 1) * sizeof(int);
    int*    off_s = (int*)w;                       w += (NN + 1) * sizeof(int);
    int*    cnt_t = (int*)w;                       w += NN * sizeof(int);
    int*    cnt_s = (int*)w;                       w += NN * sizeof(int);
    int4*   epos  = (int4*)w;                      w += (size_t)EE * sizeof(int4);
    int4*   eT    = (int4*)w;                      w += (size_t)EE * sizeof(int4);

    stats1_kernel<<<256, 256, 0, stream>>>(ea, partd);
    stats2_kernel<<<1, 256, 0, stream>>>(partd, stats);
    edgepre_kernel<<<(EE + 255) / 256, 256, 0, stream>>>(ea, stats, epre4);
    cvtw_kernel<<<(192 * HIDC + 255) / 256, 256, 0, stream>>>(
        wi, wh, ew2, eb2, nw, wi_h, wh_h, wpack);
    initxn_kernel<<<(BN + 255) / 256, 256, 0, stream>>>(pm, xncur);
    hipMemsetAsync(hnA, 0, (size_t)32 * BN * sizeof(__half2), stream);
    hipMemsetAsync(deg_t, 0, 2 * NN * sizeof(int), stream);
    hist_kernel<<<(EE + 255) / 256, 256, 0, stream>>>(eidx, deg_t, deg_s);
    scan_kernel<<<1, 1024, 0, stream>>>(deg_t, deg_s, off_t, off_s, cnt_t, cnt_s);
    fill_kernel<<<(EE + 255) / 256, 256, 0, stream>>>(eidx, cnt_t, cnt_s, epos);
    perm_kernel<<<(EE + 255) / 256, 256, 0, stream>>>(epos, epre4, eT, epreT);

    for (int t = 0; t < PREDC; t++) {
        const __half2* hnold = (t & 1) ? hnB : hnA;
        __half2*       hnnew = (t & 1) ? hnA : hnB;
        pre_kernel<<<(BN * 8 + 255) / 256, 256, 0, stream>>>(
            xncur, feat, t, xp, fb, ew1, wmean, wstd, preS, preT, wind2, out);
        edge_kernel<<<dim3(EE / 256, BB), 256, 0, stream>>>(
            eT, epreT, preS, preT, wind2, ew1, eb1, wpack, h3t, h3s);
        gather_kernel<<<(NN * 64 + 255) / 256, 256, 0, stream>>>(
            h3t, h3s, off_t, off_s, agg13);
        node_kernel<<<dim3(BN / 64, 4), 256, 0, stream>>>(
            xncur, feat, t, agg13, nb, wi_h, wh_h, bi, bh, fw, hnold, hnnew, xp);
    }
    finalout_kernel<<<(BN + 255) / 256, 256, 0, stream>>>(xp, fb, out);
}

// Round 16
// 1027.943 us; speedup vs baseline: 1.0672x; 1.0126x over previous
//
#include <hip/hip_runtime.h>
#include <hip/hip_fp16.h>
#include <cstddef>

#define BB    4
#define NN    10000
#define EE    160000
#define BN    40000      // BB*NN
#define HISTC 8
#define PREDC 12
#define TSTEP 20         // HIST+PRED
#define FEX   8
#define HIDC  64
#define EHID  32
#define EOUTC 30
#define GOUTC 13
#define GINC  22         // GOUTC + 9

typedef float v2f __attribute__((ext_vector_type(2)));
typedef _Float16 v2h __attribute__((ext_vector_type(2)));

struct alignas(16) WPack {      // 128 B: one layer-2 output channel
    __half2 w[16];   // w2 row (32 halves)
    float   nw[14];  // folded n_w row (13 + pad)
    float   b2;
    float   pad;
};

__device__ __forceinline__ float fast_rcp(float x) { return __builtin_amdgcn_rcpf(x); }
__device__ __forceinline__ float sigm(float x) {
    return fast_rcp(1.0f + __expf(-x));
}
__device__ __forceinline__ v2f sigm2(v2f x) {
    v2f r; r.x = sigm(x.x); r.y = sigm(x.y); return r;
}
__device__ __forceinline__ float tanh_fast(float x) {
    x = fminf(fmaxf(x, -15.0f), 15.0f);
    float e = __expf(2.0f * x);
    return (e - 1.0f) * fast_rcp(e + 1.0f);
}

__device__ __forceinline__ float dot2(__half2 a, __half2 b, float c) {
#if __has_builtin(__builtin_amdgcn_fdot2)
    union { __half2 h; v2h v; } ua, ub;
    ua.h = a; ub.h = b;
    return __builtin_amdgcn_fdot2(ua.v, ub.v, c, false);
#else
    float2 fa = __half22float2(a), fb = __half22float2(b);
    return c + fa.x * fb.x + fa.y * fb.y;
#endif
}

// ---------------- edge_attr stats ---------------------------------------------
__global__ __launch_bounds__(256) void stats1_kernel(const float* __restrict__ ea,
                                                     double* __restrict__ part) {
    __shared__ double sm[256][4];
    int tid = threadIdx.x;
    double s0 = 0, s1 = 0, q0 = 0, q1 = 0;
    for (int e = blockIdx.x * 256 + tid; e < EE; e += 256 * 256) {
        float2 v = reinterpret_cast<const float2*>(ea)[e];
        double v0 = (double)v.x, v1 = (double)v.y;
        s0 += v0; q0 += v0 * v0;
        s1 += v1; q1 += v1 * v1;
    }
    sm[tid][0] = s0; sm[tid][1] = s1; sm[tid][2] = q0; sm[tid][3] = q1;
    __syncthreads();
    for (int off = 128; off > 0; off >>= 1) {
        if (tid < off)
            for (int k = 0; k < 4; k++) sm[tid][k] += sm[tid + off][k];
        __syncthreads();
    }
    if (tid == 0) {
        part[blockIdx.x * 4 + 0] = sm[0][0];
        part[blockIdx.x * 4 + 1] = sm[0][1];
        part[blockIdx.x * 4 + 2] = sm[0][2];
        part[blockIdx.x * 4 + 3] = sm[0][3];
    }
}

__global__ __launch_bounds__(256) void stats2_kernel(const double* __restrict__ part,
                                                     float* __restrict__ stats) {
    __shared__ double sm[256][4];
    int tid = threadIdx.x;
    sm[tid][0] = part[tid * 4 + 0];
    sm[tid][1] = part[tid * 4 + 1];
    sm[tid][2] = part[tid * 4 + 2];
    sm[tid][3] = part[tid * 4 + 3];
    __syncthreads();
    for (int off = 128; off > 0; off >>= 1) {
        if (tid < off)
            for (int k = 0; k < 4; k++) sm[tid][k] += sm[tid + off][k];
        __syncthreads();
    }
    if (tid == 0) {
        double m0 = sm[0][0] / EE, m1 = sm[0][1] / EE;
        double v0 = (sm[0][2] - sm[0][0] * sm[0][0] / EE) / (double)(EE - 1);
        double v1 = (sm[0][3] - sm[0][1] * sm[0][1] / EE) / (double)(EE - 1);
        float sd0 = fmaxf((float)sqrt(v0 > 0 ? v0 : 0.0), 1e-6f);
        float sd1 = fmaxf((float)sqrt(v1 > 0 ? v1 : 0.0), 1e-6f);
        stats[0] = (float)m0; stats[1] = (float)m1;
        stats[2] = 1.0f / sd0; stats[3] = 1.0f / sd1;
    }
}

// ---------------- per-edge precompute + degree histogram (fused) --------------
__global__ __launch_bounds__(256) void edgepre_kernel(
    const float* __restrict__ ea, const float* __restrict__ stats,
    const int* __restrict__ eidx,
    int* __restrict__ deg_t, int* __restrict__ deg_s,
    float4* __restrict__ epre4)
{
    int e = blockIdx.x * 256 + threadIdx.x;
    if (e >= EE) return;
    float2 v = reinterpret_cast<const float2*>(ea)[e];
    float4 r;
    r.x = (v.x - stats[0]) * stats[2];
    r.y = (v.y - stats[1]) * stats[3];
    r.z = 1.0f / fmaxf(v.x, 1e-3f);
    r.w = v.y;
    epre4[e] = r;
    atomicAdd(&deg_s[eidx[e]], 1);
    atomicAdd(&deg_t[eidx[EE + e]], 1);
}

// ---------------- weight conversion + WPack build (once per call) -------------
__global__ __launch_bounds__(256) void cvtw_kernel(
    const float* __restrict__ wi, const float* __restrict__ wh,
    const float* __restrict__ ew2, const float* __restrict__ eb2,
    const float* __restrict__ nw,
    __half* __restrict__ wi_h, __half* __restrict__ wh_h,
    WPack* __restrict__ wpack)
{
    int i = blockIdx.x * 256 + threadIdx.x;
    if (i < 192 * GINC) wi_h[i] = __float2half(wi[i]);
    if (i < 192 * HIDC) wh_h[i] = __float2half(wh[i]);
    if (i < EOUTC) {
        WPack wp;
        #pragma unroll
        for (int q = 0; q < 16; q++)
            wp.w[q] = __floats2half2_rn(ew2[(2 * q) * EOUTC + i],
                                        ew2[(2 * q + 1) * EOUTC + i]);
        #pragma unroll
        for (int j = 0; j < GOUTC; j++) wp.nw[j] = nw[i * GOUTC + j];
        wp.nw[13] = 0.f;
        wp.b2 = eb2[i];
        wp.pad = 0.f;
        wpack[i] = wp;
    }
}

// ---------------- xn init -----------------------------------------------------
__global__ void initxn_kernel(const float* __restrict__ pm, float* __restrict__ xn) {
    int i = blockIdx.x * 256 + threadIdx.x;
    if (i >= BN) return;
    int b = i / NN, n = i - b * NN;
    xn[i] = pm[(b * HISTC + (HISTC - 1)) * NN + n];
}

// ---------------- CSR scan ----------------------------------------------------
__global__ __launch_bounds__(1024) void scan_kernel(
    const int* __restrict__ deg_t, const int* __restrict__ deg_s,
    int* __restrict__ off_t, int* __restrict__ off_s,
    int* __restrict__ cnt_t, int* __restrict__ cnt_s)
{
    __shared__ int pt[1024], ps[1024];
    int tid = threadIdx.x;
    int base = tid * 10;
    int st = 0, ss = 0;
    for (int k = 0; k < 10; k++) {
        int i = base + k;
        if (i < NN) { st += deg_t[i]; ss += deg_s[i]; }
    }
    pt[tid] = st; ps[tid] = ss;
    __syncthreads();
    for (int off = 1; off < 1024; off <<= 1) {
        int vt = (tid >= off) ? pt[tid - off] : 0;
        int vs = (tid >= off) ? ps[tid - off] : 0;
        __syncthreads();
        pt[tid] += vt; ps[tid] += vs;
        __syncthreads();
    }
    int ext = (tid == 0) ? 0 : pt[tid - 1];
    int exs = (tid == 0) ? 0 : ps[tid - 1];
    for (int k = 0; k < 10; k++) {
        int i = base + k;
        if (i < NN) {
            off_t[i] = ext; cnt_t[i] = ext;
            off_s[i] = exs; cnt_s[i] = exs;
            ext += deg_t[i]; exs += deg_s[i];
        }
    }
    if (tid == 0) { off_t[NN] = EE; off_s[NN] = EE; }
}

// fill+perm fused: directly scatter eT[slot]={src,tgt,pos_s}, epreT[slot]
__global__ void fillperm_kernel(const int* __restrict__ eidx,
                                const float4* __restrict__ epre4,
                                int* __restrict__ cnt_t, int* __restrict__ cnt_s,
                                int4* __restrict__ eT, float4* __restrict__ epreT)
{
    int e = blockIdx.x * 256 + threadIdx.x;
    if (e >= EE) return;
    int s = eidx[e];
    int g = eidx[EE + e];
    int pt = atomicAdd(&cnt_t[g], 1);
    int ps = atomicAdd(&cnt_s[s], 1);
    int4 r; r.x = s; r.y = g; r.z = ps; r.w = 0;
    eT[pt] = r;
    epreT[pt] = epre4[e];
}

// ---------------- per-step node precompute (fp16 tables) + xn/out finalize ----
__global__ __launch_bounds__(256) void pre_kernel(
    float* __restrict__ xncur, const float* __restrict__ feature, int t,
    const float* __restrict__ xp,      // [4][BN] fc partials from node_kernel
    const float* __restrict__ fb,
    const float* __restrict__ ew1,
    const float* __restrict__ wmean, const float* __restrict__ wstd,
    __half* __restrict__ preS, __half* __restrict__ preT,
    float2* __restrict__ wind2, float* __restrict__ out)
{
    __shared__ alignas(16) float w1s[18 * EHID];
    for (int i = threadIdx.x; i < 18 * EHID; i += 256) w1s[i] = ew1[i];
    __syncthreads();
    int idx = blockIdx.x * 256 + threadIdx.x;
    if (idx >= BN * 8) return;
    int i = idx >> 3;
    int c = idx & 7;
    int b = i / NN, n = i - b * NN;
    float x0;
    if (t == 0) {
        x0 = xncur[i];
    } else {
        x0 = (xp[i] + xp[BN + i]) + (xp[2 * BN + i] + xp[3 * BN + i]) + fb[0];
        if (c == 0) {
            xncur[i] = x0;
            out[(size_t)i * PREDC + (t - 1)] = x0;
        }
    }
    float x[9];
    x[0] = x0;
    {
        const float4* fp = reinterpret_cast<const float4*>(
            feature + (((size_t)b * TSTEP + HISTC + t) * NN + n) * FEX);
        float4 u = fp[0], v = fp[1];
        x[1] = u.x; x[2] = u.y; x[3] = u.z; x[4] = u.w;
        x[5] = v.x; x[6] = v.y; x[7] = v.z; x[8] = v.w;
    }
    float4 aS = {0.f, 0.f, 0.f, 0.f}, aT = {0.f, 0.f, 0.f, 0.f};
    #pragma unroll
    for (int k = 0; k < 9; k++) {
        float4 wS = reinterpret_cast<const float4*>(&w1s[k * EHID])[c];
        float4 wT = reinterpret_cast<const float4*>(&w1s[(9 + k) * EHID])[c];
        aS.x += x[k] * wS.x; aS.y += x[k] * wS.y; aS.z += x[k] * wS.z; aS.w += x[k] * wS.w;
        aT.x += x[k] * wT.x; aT.y += x[k] * wT.y; aT.z += x[k] * wT.z; aT.w += x[k] * wT.w;
    }
    union { uint2 u; __half h[4]; } sv, tv;
    sv.h[0] = __float2half(aS.x); sv.h[1] = __float2half(aS.y);
    sv.h[2] = __float2half(aS.z); sv.h[3] = __float2half(aS.w);
    tv.h[0] = __float2half(aT.x); tv.h[1] = __float2half(aT.y);
    tv.h[2] = __float2half(aT.z); tv.h[3] = __float2half(aT.w);
    reinterpret_cast<uint2*>(preS + (size_t)i * EHID)[c] = sv.u;
    reinterpret_cast<uint2*>(preT + (size_t)i * EHID)[c] = tv.u;
    if (c == 1) {
        float sd0 = fmaxf(wstd[0], 1e-6f), sd1 = fmaxf(wstd[1], 1e-6f);
        float speed = fmaxf(x[7] * sd0 + wmean[0], 0.f);
        float wdir  = (x[8] * sd1 + wmean[1]) * 0.017453292519943295f;
        float2 wv; wv.x = 3.0f * speed; wv.y = wdir;
        wind2[i] = wv;
    }
}

__global__ __launch_bounds__(256) void finalout_kernel(
    const float* __restrict__ xp, const float* __restrict__ fb,
    float* __restrict__ out)
{
    int i = blockIdx.x * 256 + threadIdx.x;
    if (i >= BN) return;
    out[(size_t)i * PREDC + (PREDC - 1)] =
        (xp[i] + xp[BN + i]) + (xp[2 * BN + i] + xp[3 * BN + i]) + fb[0];
}

// ---------------- edge MLP, tgt-slot order, 1 batch/thread, grid (625,4) ------
__global__ __launch_bounds__(256) void edge_kernel(
    const int4* __restrict__ eT, const float4* __restrict__ epreT,
    const __half* __restrict__ preS, const __half* __restrict__ preT,
    const float2* __restrict__ wind2,
    const float* __restrict__ ew1, const float* __restrict__ eb1,
    const WPack* __restrict__ wpack,
    __half* __restrict__ h3t, __half* __restrict__ h3s)
{
    int i = blockIdx.x * 256 + threadIdx.x;   // slot (EE == 625*256, no tail)
    int b = blockIdx.y;
    int4 et = eT[i];
    int s = et.x, g = et.y, ps = et.z;
    float4 ep = epreT[i];          // {ean0, ean1, 1/dist, direc}

    size_t iS = (size_t)b * NN + s, iT = (size_t)b * NN + g;
    float2 wv2 = wind2[iS];
    float ew = fmaxf(wv2.x * __cosf(fabsf(ep.w - wv2.y)) * ep.z, 0.f);

    union alignas(16) { uint4 u[4]; __half2 h2[16]; } RS, RT;
    {
        const uint4* p;
        p = reinterpret_cast<const uint4*>(preS + iS * EHID);
        RS.u[0] = p[0]; RS.u[1] = p[1]; RS.u[2] = p[2]; RS.u[3] = p[3];
        p = reinterpret_cast<const uint4*>(preT + iT * EHID);
        RT.u[0] = p[0]; RT.u[1] = p[1]; RT.u[2] = p[2]; RT.u[3] = p[3];
    }

    const v2f* W18 = reinterpret_cast<const v2f*>(ew1 + 18 * EHID);
    const v2f* W19 = reinterpret_cast<const v2f*>(ew1 + 19 * EHID);
    const v2f* W20 = reinterpret_cast<const v2f*>(ew1 + 20 * EHID);
    const v2f* B1  = reinterpret_cast<const v2f*>(eb1);
    float ean0 = ep.x, ean1 = ep.y;
    __half2 h1h[16];
    #pragma unroll
    for (int q = 0; q < 16; q++) {
        v2f u = W18[q] * ean0 + W19[q] * ean1 + B1[q] + W20[q] * ew;
        float2 rs = __half22float2(RS.h2[q]);
        float2 rt = __half22float2(RT.h2[q]);
        u.x += rs.x + rt.x;
        u.y += rs.y + rt.y;
        v2f sg = sigm2(u);
        h1h[q] = __floats2half2_rn(sg.x, sg.y);
    }

    v2f h3p[7];
    #pragma unroll
    for (int j = 0; j < 7; j++) { h3p[j].x = 0.f; h3p[j].y = 0.f; }
    for (int o = 0; o < EOUTC; o++) {
        const WPack* W = wpack + o;
        float acc0 = W->b2, acc1 = 0.f;
        #pragma unroll
        for (int q = 0; q < 16; q += 2) {
            acc0 = dot2(h1h[q],     W->w[q],     acc0);
            acc1 = dot2(h1h[q + 1], W->w[q + 1], acc1);
        }
        float h2v = sigm(acc0 + acc1);
        const v2f* nr = reinterpret_cast<const v2f*>(W->nw);
        #pragma unroll
        for (int j = 0; j < 7; j++) h3p[j] += nr[j] * h2v;
    }

    union alignas(16) { uint4 u[2]; __half2 h2[8]; } r;
    #pragma unroll
    for (int j = 0; j < 7; j++) r.h2[j] = __floats2half2_rn(h3p[j].x, h3p[j].y);
    r.h2[7] = __floats2half2_rn(0.f, 0.f);
    {
        __half* oT = h3t + ((size_t)b * EE + i) * 16;     // coalesced
        reinterpret_cast<uint4*>(oT)[0] = r.u[0];
        reinterpret_cast<uint4*>(oT)[1] = r.u[1];
        __half* oS = h3s + ((size_t)b * EE + ps) * 16;    // scattered
        reinterpret_cast<uint4*>(oS)[0] = r.u[0];
        reinterpret_cast<uint4*>(oS)[1] = r.u[1];
    }
}

// ---------------- gather + gnn-out sigmoid -> fp16 xcagg ----------------------
// lane = b*16+ch. ch<13: sigm(sum +- nb). ch==13: xn. ch 14/15: 0.
__global__ __launch_bounds__(256) void gather_kernel(
    const __half* __restrict__ h3t, const __half* __restrict__ h3s,
    const int* __restrict__ off_t, const int* __restrict__ off_s,
    const float* __restrict__ nb, const float* __restrict__ xncur,
    __half* __restrict__ xcagg)
{
    int n = (blockIdx.x * 256 + threadIdx.x) >> 6;
    if (n >= NN) return;
    n = __builtin_amdgcn_readfirstlane(n);
    int lane = threadIdx.x & 63;
    int b = lane >> 4, ch = lane & 15;
    const __half* ht = h3t + (size_t)b * EE * 16 + ch;
    const __half* hs = h3s + (size_t)b * EE * 16 + ch;
    float a0 = 0.f, a1 = 0.f, a2 = 0.f, a3 = 0.f;
    {
        int i0 = off_t[n], i1 = off_t[n + 1];
        int i = i0;
        for (; i + 4 <= i1; i += 4) {
            a0 += __half2float(ht[(size_t)(i + 0) * 16]);
            a1 += __half2float(ht[(size_t)(i + 1) * 16]);
            a2 += __half2float(ht[(size_t)(i + 2) * 16]);
            a3 += __half2float(ht[(size_t)(i + 3) * 16]);
        }
        for (; i < i1; i++) a0 += __half2float(ht[(size_t)i * 16]);
    }
    {
        int i0 = off_s[n], i1 = off_s[n + 1];
        int i = i0;
        for (; i + 4 <= i1; i += 4) {
            a0 -= __half2float(hs[(size_t)(i + 0) * 16]);
            a1 -= __half2float(hs[(size_t)(i + 1) * 16]);
            a2 -= __half2float(hs[(size_t)(i + 2) * 16]);
            a3 -= __half2float(hs[(size_t)(i + 3) * 16]);
        }
        for (; i < i1; i++) a0 -= __half2float(hs[(size_t)i * 16]);
    }
    float acc = (a0 + a1) + (a2 + a3);
    float val;
    if (ch < GOUTC) {
        val = sigm(acc + nb[ch]);
    } else if (ch == GOUTC) {
        val = xncur[(size_t)b * NN + n];
    } else {
        val = 0.f;
    }
    xcagg[((size_t)b * NN + n) * 16 + ch] = __float2half(val);
}

// ---------------- node: GRU (fp16 dot2) + fc partial --------------------------
// grid (BN/64, 4); wave w of block (.,jb) handles dims [jb*16 + w*4, +4).
// xc[0..13] comes pre-sigmoided fp16 from xcagg; features appended.
__global__ __launch_bounds__(256) void node_kernel(
    const __half* __restrict__ xcagg, const float* __restrict__ feature, int t,
    const __half* __restrict__ wi_h, const __half* __restrict__ wh_h,
    const float* __restrict__ bi, const float* __restrict__ bh,
    const float* __restrict__ fw,
    const __half2* __restrict__ hnold, __half2* __restrict__ hnnew,
    float* __restrict__ xp)
{
    __shared__ float xpart[4][64];
    int lane = threadIdx.x & 63;
    int wav  = threadIdx.x >> 6;
    int jb   = blockIdx.y;
    int node = blockIdx.x * 64 + lane;
    int b = node / NN;
    int n = node - b * NN;

    __half2 xch[11];
    {
        union alignas(16) { uint4 u[2]; __half2 h2[8]; } X;
        const uint4* xp16 = reinterpret_cast<const uint4*>(xcagg + (size_t)node * 16);
        X.u[0] = xp16[0]; X.u[1] = xp16[1];
        #pragma unroll
        for (int p = 0; p < 7; p++) xch[p] = X.h2[p];   // ch 0..13 (incl. xn)
    }
    {
        const float4* fp = reinterpret_cast<const float4*>(
            feature + (((size_t)b * TSTEP + HISTC + t) * NN + n) * FEX);
        float4 u = fp[0], v = fp[1];
        xch[7]  = __floats2half2_rn(u.x, u.y);
        xch[8]  = __floats2half2_rn(u.z, u.w);
        xch[9]  = __floats2half2_rn(v.x, v.y);
        xch[10] = __floats2half2_rn(v.z, v.w);
    }

    __half2 hh[32];
    #pragma unroll
    for (int p = 0; p < 32; p++) hh[p] = hnold[(size_t)p * BN + node];

    float xsum = 0.f;
    #pragma unroll
    for (int jj2 = 0; jj2 < 2; jj2++) {
        int j0 = __builtin_amdgcn_readfirstlane(jb * 16 + wav * 4 + jj2 * 2);
        union { __half2 h; __half v[2]; } holdw;
        holdw.h = hnold[(size_t)(j0 >> 1) * BN + node];
        float hnew2[2];
        #pragma unroll
        for (int d = 0; d < 2; d++) {
            int j = j0 + d;
            float ir = bi[j], iz = bi[64 + j], in_ = bi[128 + j];
            const __half2* wr0 = reinterpret_cast<const __half2*>(wi_h + (size_t)j * GINC);
            const __half2* wr1 = reinterpret_cast<const __half2*>(wi_h + (size_t)(64 + j) * GINC);
            const __half2* wr2 = reinterpret_cast<const __half2*>(wi_h + (size_t)(128 + j) * GINC);
            #pragma unroll
            for (int p = 0; p < 11; p++) {
                ir  = dot2(xch[p], wr0[p], ir);
                iz  = dot2(xch[p], wr1[p], iz);
                in_ = dot2(xch[p], wr2[p], in_);
            }
            float hr0 = bh[j], hz0 = bh[64 + j], hn0 = bh[128 + j];
            float hr1 = 0.f, hz1 = 0.f, hn1 = 0.f;
            const __half2* vr0 = reinterpret_cast<const __half2*>(wh_h + (size_t)j * HIDC);
            const __half2* vr1 = reinterpret_cast<const __half2*>(wh_h + (size_t)(64 + j) * HIDC);
            const __half2* vr2 = reinterpret_cast<const __half2*>(wh_h + (size_t)(128 + j) * HIDC);
            #pragma unroll
            for (int p = 0; p < 32; p += 2) {
                hr0 = dot2(hh[p],     vr0[p],     hr0);
                hz0 = dot2(hh[p],     vr1[p],     hz0);
                hn0 = dot2(hh[p],     vr2[p],     hn0);
                hr1 = dot2(hh[p + 1], vr0[p + 1], hr1);
                hz1 = dot2(hh[p + 1], vr1[p + 1], hz1);
                hn1 = dot2(hh[p + 1], vr2[p + 1], hn1);
            }
            float r  = sigm(ir + hr0 + hr1);
            float z  = sigm(iz + hz0 + hz1);
            float nn = tanh_fast(in_ + r * (hn0 + hn1));
            float hold = __half2float(holdw.v[d]);
            float hnew = (1.f - z) * nn + z * hold;
            hnew2[d] = hnew;
            xsum += hnew * fw[j];
        }
        hnnew[(size_t)(j0 >> 1) * BN + node] = __floats2half2_rn(hnew2[0], hnew2[1]);
    }
    xpart[wav][lane] = xsum;
    __syncthreads();
    if (wav == 0) {
        float tot = xpart[0][lane] + xpart[1][lane] + xpart[2][lane] + xpart[3][lane];
        xp[(size_t)jb * BN + node] = tot;
    }
}

extern "C" void kernel_launch(void* const* d_in, const int* in_sizes, int n_in,
                              void* d_out, int out_size, void* d_ws, size_t ws_size,
                              hipStream_t stream)
{
    const float* pm    = (const float*)d_in[0];
    const float* feat  = (const float*)d_in[1];
    const float* ea    = (const float*)d_in[2];
    const float* wmean = (const float*)d_in[3];
    const float* wstd  = (const float*)d_in[4];
    const float* ew1   = (const float*)d_in[5];
    const float* eb1   = (const float*)d_in[6];
    const float* ew2   = (const float*)d_in[7];
    const float* eb2   = (const float*)d_in[8];
    const float* nw    = (const float*)d_in[9];
    const float* nb    = (const float*)d_in[10];
    const float* wi    = (const float*)d_in[11];
    const float* wh    = (const float*)d_in[12];
    const float* bi    = (const float*)d_in[13];
    const float* bh    = (const float*)d_in[14];
    const float* fw    = (const float*)d_in[15];
    const float* fb    = (const float*)d_in[16];
    const int*   eidx  = (const int*)d_in[17];
    float* out = (float*)d_out;

    char* w = (char*)d_ws;
    double* partd = (double*)w;                    w += 256 * 4 * sizeof(double);
    float*  stats = (float*)w;                     w += 16 * sizeof(float);
    WPack*  wpack = (WPack*)w;                     w += EOUTC * sizeof(WPack);
    float4* epre4 = (float4*)w;                    w += (size_t)EE * sizeof(float4);
    float4* epreT = (float4*)w;                    w += (size_t)EE * sizeof(float4);
    float*  xncur = (float*)w;                     w += (size_t)BN * sizeof(float);
    float*  xp    = (float*)w;                     w += (size_t)4 * BN * sizeof(float);
    __half2* hnA  = (__half2*)w;                   w += (size_t)32 * BN * sizeof(__half2);
    __half2* hnB  = (__half2*)w;                   w += (size_t)32 * BN * sizeof(__half2);
    __half* xcagg = (__half*)w;                    w += (size_t)BN * 16 * sizeof(__half);
    __half* preS  = (__half*)w;                    w += (size_t)BN * EHID * sizeof(__half);
    __half* preT  = (__half*)w;                    w += (size_t)BN * EHID * sizeof(__half);
    float2* wind2 = (float2*)w;                    w += (size_t)BN * sizeof(float2);
    __half* h3t   = (__half*)w;                    w += (size_t)BB * EE * 16 * sizeof(__half);
    __half* h3s   = (__half*)w;                    w += (size_t)BB * EE * 16 * sizeof(__half);
    __half* wi_h  = (__half*)w;                    w += (size_t)192 * GINC * sizeof(__half);
    __half* wh_h  = (__half*)w;                    w += (size_t)192 * HIDC * sizeof(__half);
    int*    deg_t = (int*)w;                       w += NN * sizeof(int);
    int*    deg_s = (int*)w;                       w += NN * sizeof(int);
    int*    off_t = (int*)w;                       w += (NN + 1) * sizeof(int);
    int*    off_s = (int*)w;                       w += (NN + 1) * sizeof(int);
    int*    cnt_t = (int*)w;                       w += NN * sizeof(int);
    int*    cnt_s = (int*)w;                       w += NN * sizeof(int);
    int4*   eT    = (int4*)w;                      w += (size_t)EE * sizeof(int4);

    stats1_kernel<<<256, 256, 0, stream>>>(ea, partd);
    stats2_kernel<<<1, 256, 0, stream>>>(partd, stats);
    hipMemsetAsync(deg_t, 0, 2 * NN * sizeof(int), stream);
    edgepre_kernel<<<(EE + 255) / 256, 256, 0, stream>>>(
        ea, stats, eidx, deg_t, deg_s, epre4);
    cvtw_kernel<<<(192 * HIDC + 255) / 256, 256, 0, stream>>>(
        wi, wh, ew2, eb2, nw, wi_h, wh_h, wpack);
    initxn_kernel<<<(BN + 255) / 256, 256, 0, stream>>>(pm, xncur);
    hipMemsetAsync(hnA, 0, (size_t)32 * BN * sizeof(__half2), stream);
    scan_kernel<<<1, 1024, 0, stream>>>(deg_t, deg_s, off_t, off_s, cnt_t, cnt_s);
    fillperm_kernel<<<(EE + 255) / 256, 256, 0, stream>>>(
        eidx, epre4, cnt_t, cnt_s, eT, epreT);

    for (int t = 0; t < PREDC; t++) {
        const __half2* hnold = (t & 1) ? hnB : hnA;
        __half2*       hnnew = (t & 1) ? hnA : hnB;
        pre_kernel<<<(BN * 8 + 255) / 256, 256, 0, stream>>>(
            xncur, feat, t, xp, fb, ew1, wmean, wstd, preS, preT, wind2, out);
        edge_kernel<<<dim3(EE / 256, BB), 256, 0, stream>>>(
            eT, epreT, preS, preT, wind2, ew1, eb1, wpack, h3t, h3s);
        gather_kernel<<<(NN * 64 + 255) / 256, 256, 0, stream>>>(
            h3t, h3s, off_t, off_s, nb, xncur, xcagg);
        node_kernel<<<dim3(BN / 64, 4), 256, 0, stream>>>(
            xcagg, feat, t, wi_h, wh_h, bi, bh, fw, hnold, hnnew, xp);
    }
    finalout_kernel<<<(BN + 255) / 256, 256, 0, stream>>>(xp, fb, out);
}